// Round 8
// baseline (392.484 us; speedup 1.0000x reference)
//
#include <hip/hip_runtime.h>
#include <cstdint>
#include <cstddef>

typedef unsigned short u16t;
typedef __bf16 bf16x8_t __attribute__((ext_vector_type(8)));
typedef float f32x4_t __attribute__((ext_vector_type(4)));
typedef float f32x16_t __attribute__((ext_vector_type(16)));

#define MFMA_BF16 __builtin_amdgcn_mfma_f32_16x16x32_bf16
#define MFMA32    __builtin_amdgcn_mfma_f32_32x32x16_bf16

__device__ __forceinline__ u16t f2bf(float f) {
    uint32_t u = __builtin_bit_cast(uint32_t, f);
    u += 0x7fffu + ((u >> 16) & 1u);   // RNE
    return (u16t)(u >> 16);
}

__device__ __forceinline__ uint32_t pk2bf(float a, float b) {
    return (uint32_t)f2bf(a) | ((uint32_t)f2bf(b) << 16);
}

__device__ __forceinline__ float bflo(uint32_t u) {
    return __builtin_bit_cast(float, u << 16);
}
__device__ __forceinline__ float bfhi(uint32_t u) {
    return __builtin_bit_cast(float, u & 0xffff0000u);
}

__device__ __forceinline__ bf16x8_t ld_frag(const u16t* p) {
    return __builtin_bit_cast(bf16x8_t, *(const uint4*)p);
}

// single-instruction RNE pack of two f32 -> bf16x2
__device__ __forceinline__ uint32_t cvtpk(float lo, float hi) {
    uint32_t r;
    asm("v_cvt_pk_bf16_f32 %0, %1, %2" : "=v"(r) : "v"(lo), "v"(hi));
    return r;
}
// a[32:63] <-> b[0:31]  (gfx950 v_permlane32_swap_b32)
__device__ __forceinline__ void swap32(uint32_t& a, uint32_t& b) {
    asm("v_permlane32_swap_b32 %0, %1" : "+v"(a), "+v"(b));
}

// async global->LDS DMA, 16 B per lane. lds base must be wave-uniform;
// lane i deposits at lds + i*16 B. Swizzling is done on the GLOBAL address.
__device__ __forceinline__ void gl_lds16(const u16t* g, u16t* l) {
    __builtin_amdgcn_global_load_lds(
        (const __attribute__((address_space(1))) void*)g,
        (__attribute__((address_space(3))) void*)l, 16, 0, 0);
}

// ---------------- fused cast f32 -> bf16 for x and ctx, 4 elems/thread ----------------
__global__ void cast2_bf16_kernel(const float* __restrict__ s0, u16t* __restrict__ d0, int n0,
                                  const float* __restrict__ s1, u16t* __restrict__ d1, int n1) {
    int i = blockIdx.x * blockDim.x + threadIdx.x;
    const float* s; u16t* d;
    if (i < n0) { s = s0; d = d0; }
    else { i -= n0; if (i >= n1) return; s = s1; d = d1; }
    float4 v = ((const float4*)s)[i];
    uint2 o;
    o.x = pk2bf(v.x, v.y);
    o.y = pk2bf(v.z, v.w);
    ((uint2*)d)[i] = o;
}

// ---------------- fused transpose+cast of all 4 weights: W[K][1024] -> Wt[1024][K] ----
__global__ void transpose4_kernel(const float* __restrict__ Wq, const float* __restrict__ Wk,
                                  const float* __restrict__ Wv, const float* __restrict__ Wo,
                                  u16t* __restrict__ Wqt, u16t* __restrict__ Wkt,
                                  u16t* __restrict__ Wvt, u16t* __restrict__ Wot) {
    const int z = blockIdx.z;
    const float* W = z == 0 ? Wq : (z == 1 ? Wk : (z == 2 ? Wv : Wo));
    u16t* Wt      = z == 0 ? Wqt : (z == 1 ? Wkt : (z == 2 ? Wvt : Wot));
    const int K   = (z == 1 || z == 2) ? 768 : 1024;
    const int N = 1024;
    int n0 = blockIdx.x * 32, k0 = blockIdx.y * 32;
    if (k0 >= K) return;
    __shared__ float tile[32][33];
    int tx = threadIdx.x, ty = threadIdx.y;
    for (int i = ty; i < 32; i += 8)
        tile[i][tx] = W[(size_t)(k0 + i) * N + n0 + tx];
    __syncthreads();
    for (int i = ty; i < 32; i += 8)
        Wt[(size_t)(n0 + i) * K + k0 + tx] = f2bf(tile[tx][i]);
}

// ---------------- GEMM core: C = A[M][K]bf16 @ Bt[N][K]^T, tile 128x64 ----------------
// DMA double-buffer, one barrier per K-step.
// mode 0: bf16 head-split store out[(h*4096+row)*128+d] * oscale  (Q/K)
// mode 2: bf16 transposed store out[(h*128+d)*4096+row]           (V^T)
// mode 3: f32 store out[row*1024+c] + bias[c]                     (final)
__device__ __forceinline__ void gemm_core(
    const u16t* __restrict__ A, const u16t* __restrict__ Bt,
    int K, void* __restrict__ outp, const float* __restrict__ bias,
    int mode, float oscale, int bm, int bn)
{
    __shared__ __align__(16) u16t As[2][128 * 64];
    __shared__ __align__(16) u16t Bs[2][64 * 64];
    const int tid = threadIdx.x;
    const int wave = tid >> 6, lane = tid & 63;
    const int wm = wave & 1, wn = wave >> 1;
    const int quad = lane >> 4, l16 = lane & 15;

    const int l8r = lane >> 3, l8c = lane & 7;
    const int cgx = (l8c ^ l8r) * 8;

    f32x4_t acc[4][2];
#pragma unroll
    for (int i = 0; i < 4; ++i)
#pragma unroll
        for (int j = 0; j < 2; ++j) acc[i][j] = (f32x4_t){0.f, 0.f, 0.f, 0.f};

    const int nk = K >> 6;

#pragma unroll
    for (int it = 0; it < 4; ++it) {
        int rb = wave * 32 + it * 8;
        gl_lds16(&A[(size_t)(bm + rb + l8r) * K + cgx], &As[0][rb * 64]);
    }
#pragma unroll
    for (int it = 0; it < 2; ++it) {
        int rb = wave * 16 + it * 8;
        gl_lds16(&Bt[(size_t)(bn + rb + l8r) * K + cgx], &Bs[0][rb * 64]);
    }

    for (int ki = 0; ki < nk; ++ki) {
        const int buf = ki & 1;
        __syncthreads();

        if (ki + 1 < nk) {
            const int kc = (ki + 1) << 6;
#pragma unroll
            for (int it = 0; it < 4; ++it) {
                int rb = wave * 32 + it * 8;
                gl_lds16(&A[(size_t)(bm + rb + l8r) * K + kc + cgx], &As[buf ^ 1][rb * 64]);
            }
#pragma unroll
            for (int it = 0; it < 2; ++it) {
                int rb = wave * 16 + it * 8;
                gl_lds16(&Bt[(size_t)(bn + rb + l8r) * K + kc + cgx], &Bs[buf ^ 1][rb * 64]);
            }
        }

#pragma unroll
        for (int ks = 0; ks < 2; ++ks) {
            bf16x8_t af[4], bfv[2];
#pragma unroll
            for (int i = 0; i < 4; ++i) {
                int r = wm * 64 + i * 16 + l16;
                af[i] = ld_frag(&As[buf][r * 64 + (((ks * 4 + quad) ^ (r & 7)) * 8)]);
            }
#pragma unroll
            for (int j = 0; j < 2; ++j) {
                int r = wn * 32 + j * 16 + l16;
                bfv[j] = ld_frag(&Bs[buf][r * 64 + (((ks * 4 + quad) ^ (r & 7)) * 8)]);
            }
#pragma unroll
            for (int i = 0; i < 4; ++i)
#pragma unroll
                for (int j = 0; j < 2; ++j)
                    acc[i][j] = MFMA_BF16(af[i], bfv[j], acc[i][j], 0, 0, 0);
        }
    }

    if (mode == 3) {
        float* out = (float*)outp;
#pragma unroll
        for (int j = 0; j < 2; ++j) {
            int c = bn + wn * 32 + j * 16 + l16;
            float b = bias[c];
#pragma unroll
            for (int i = 0; i < 4; ++i) {
                int rb = bm + wm * 64 + i * 16 + quad * 4;
#pragma unroll
                for (int r = 0; r < 4; ++r)
                    out[(size_t)(rb + r) * 1024 + c] = acc[i][j][r] + b;
            }
        }
    } else if (mode == 2) {
        u16t* out = (u16t*)outp;
#pragma unroll
        for (int i = 0; i < 4; ++i)
#pragma unroll
            for (int j = 0; j < 2; ++j) {
                int rb = bm + wm * 64 + i * 16 + quad * 4;
                int c = bn + wn * 32 + j * 16 + l16;
                int h = c >> 7, d = c & 127;
                uint2 pk;
                pk.x = pk2bf(acc[i][j][0], acc[i][j][1]);
                pk.y = pk2bf(acc[i][j][2], acc[i][j][3]);
                *(uint2*)&out[((size_t)h * 128 + d) * 4096 + rb] = pk;
            }
    } else {
        u16t* out = (u16t*)outp;
#pragma unroll
        for (int i = 0; i < 4; ++i)
#pragma unroll
            for (int j = 0; j < 2; ++j) {
                int rb = bm + wm * 64 + i * 16 + quad * 4;
                int c = bn + wn * 32 + j * 16 + l16;
                int h = c >> 7, d = c & 127;
#pragma unroll
                for (int r = 0; r < 4; ++r)
                    out[((size_t)h * 4096 + rb + r) * 128 + d] = f2bf(acc[i][j][r] * oscale);
            }
    }
}

__global__ __launch_bounds__(256) void gemm_bf16_kernel(
    const u16t* __restrict__ A, const u16t* __restrict__ Bt,
    int K, void* __restrict__ outp, const float* __restrict__ bias,
    int mode, float oscale)
{
    gemm_core(A, Bt, K, outp, bias, mode, oscale, blockIdx.y * 128, blockIdx.x * 64);
}

// ---------------- fused Q/K/V projections: grid.z selects the GEMM ----------------
__global__ __launch_bounds__(256) void qkv_kernel(
    const u16t* __restrict__ x_bf, const u16t* __restrict__ ctx_bf,
    const u16t* __restrict__ Wqt, const u16t* __restrict__ Wkt,
    const u16t* __restrict__ Wvt,
    u16t* __restrict__ Qh, u16t* __restrict__ Kh, u16t* __restrict__ Vt,
    float qscale)
{
    const int z = blockIdx.z;
    const u16t* A  = (z == 0) ? x_bf : ctx_bf;
    const u16t* Bt = (z == 0) ? Wqt : ((z == 1) ? Wkt : Wvt);
    void* outp     = (z == 0) ? (void*)Qh : ((z == 1) ? (void*)Kh : (void*)Vt);
    const int K    = (z == 0) ? 1024 : 768;
    const int mode = (z == 2) ? 2 : 0;
    const float sc = (z == 0) ? qscale : 1.0f;
    gemm_core(A, Bt, K, outp, nullptr, mode, sc, blockIdx.y * 128, blockIdx.x * 64);
}

// ---------------- flash attention v10: zero-LDS, zero-barrier, register-resident ----------------
// v9 post-mortem: bank conflicts fixed (1.26e7 -> 4.2e6) but dur unchanged -> the
// barrier + vmcnt(0) drain of the 2-phase loop is the binding constraint, not LDS.
// v10: K and V tiles live in REGISTERS, loaded directly from global (L1/L2 serve the
// 4x intra-block reuse). No LDS, no __syncthreads, no DMA in the whole kernel.
// Per iter per wave: 16 global_load_dwordx4 (gather) + 16 MFMA32 + softmax.
// Single-buffered kf/vf: loads refill frags right after their last MFMA use; one full
// iteration (~3k cyc) covers L2 latency. In-order vmcnt: waiting on kf leaves the
// later-issued V loads in flight (counted-vmcnt semantics, compiler-managed).
// Deferred PV (v8-proven): PV[t-1] runs at iter t from pf/vf of the previous iter,
// independent of QK^T[t] -> both MFMA clusters fill the pipe back-to-back.
__global__ __launch_bounds__(256, 2) void flash_kernel(
    const u16t* __restrict__ Qh, const u16t* __restrict__ Kh,
    const u16t* __restrict__ Vtg, u16t* __restrict__ Op0,
    u16t* __restrict__ Op1, float* __restrict__ lp)
{
    const int h = blockIdx.y;
    const int q0 = blockIdx.x * 128;
    const int z = blockIdx.z;
    const int tid = threadIdx.x;
    const int wave = tid >> 6, lane = tid & 63;
    const int l31 = lane & 31, hh = lane >> 5;
    const int NT = 64;

    const u16t* Kg = Kh + (size_t)h * 4096 * 128 + (size_t)z * 2048 * 128;
    const u16t* Vg = Vtg + (size_t)h * 128 * 4096 + z * 2048;

    // ---- Q fragments direct from global (v7-proven pattern; one-time) ----
    bf16x8_t qf[8];
    {
        const u16t* Qr = Qh + ((size_t)h * 4096 + q0 + wave * 32 + l31) * 128 + hh * 8;
#pragma unroll
        for (int s = 0; s < 8; ++s) qf[s] = ld_frag(Qr + s * 16);
    }

    // per-lane tile base addresses
    const u16t* Kr0 = Kg + (size_t)l31 * 128 + hh * 8;    // + t*32*128 for tile t
    const u16t* Vr0 = Vg + (size_t)l31 * 4096 + hh * 8;   // + dg*32*4096 + t*32

    // ---- prologue: K[0] into kf ----
    bf16x8_t kf[8];
#pragma unroll
    for (int s = 0; s < 8; ++s) kf[s] = ld_frag(Kr0 + s * 16);

    bf16x8_t vf0[4], vf1[4];   // V tile (k 0-15 / 16-31 halves per d-group)
    f32x16_t Ow[4];
#pragma unroll
    for (int dg = 0; dg < 4; ++dg)
#pragma unroll
        for (int r = 0; r < 16; ++r) Ow[dg][r] = 0.f;

    float lsum = 0.f;
    bf16x8_t pf0, pf1;         // P of tile t-1, consumed at iter t

    for (int t = 0; t < NT; ++t) {
        // ---- QK^T[t] from kf ----
        f32x16_t Sa, Sb;
#pragma unroll
        for (int r = 0; r < 16; ++r) { Sa[r] = 0.f; Sb[r] = 0.f; }
        __builtin_amdgcn_s_setprio(1);
#pragma unroll
        for (int s = 0; s < 8; s += 2) {
            Sa = MFMA32(kf[s], qf[s], Sa, 0, 0, 0);
            Sb = MFMA32(kf[s + 1], qf[s + 1], Sb, 0, 0, 0);
        }
        // ---- PV[t-1]: independent of QK^T[t], fills the MFMA pipe ----
        if (t >= 1) {
#pragma unroll
            for (int dg = 0; dg < 4; ++dg) {
                Ow[dg] = MFMA32(vf0[dg], pf0, Ow[dg], 0, 0, 0);
                Ow[dg] = MFMA32(vf1[dg], pf1, Ow[dg], 0, 0, 0);
            }
        }
        __builtin_amdgcn_s_setprio(0);

        // ---- prefetch K[t+1] into kf (frags dead after QK^T above) ----
        if (t + 1 < NT) {
            const u16t* Kr = Kr0 + (size_t)(t + 1) * 4096;
#pragma unroll
            for (int s = 0; s < 8; ++s) kf[s] = ld_frag(Kr + s * 16);
        }
        // ---- load V[t] into vf (frags dead after PV[t-1] above) ----
        {
            const u16t* Vr = Vr0 + t * 32;
#pragma unroll
            for (int dg = 0; dg < 4; ++dg) {
                const u16t* vrp = Vr + (size_t)dg * 32 * 4096;
                vf0[dg] = ld_frag(vrp);
                vf1[dg] = ld_frag(vrp + 16);
            }
        }

        // ---- softmax[t] -> pf for next iter's PV ----
        float p[16];
#pragma unroll
        for (int r = 0; r < 16; ++r)
            p[r] = __builtin_amdgcn_exp2f(Sa[r] + Sb[r]);
        lsum += ((((p[0] + p[1]) + (p[2] + p[3])) + ((p[4] + p[5]) + (p[6] + p[7])))
              + (((p[8] + p[9]) + (p[10] + p[11])) + ((p[12] + p[13]) + (p[14] + p[15]))));

        uint32_t w0 = cvtpk(p[0], p[1]),   w2 = cvtpk(p[4], p[5]);
        uint32_t w1 = cvtpk(p[2], p[3]),   w3 = cvtpk(p[6], p[7]);
        swap32(w0, w2); swap32(w1, w3);    // words for k-step 0
        uint32_t y0 = cvtpk(p[8], p[9]),   y2 = cvtpk(p[12], p[13]);
        uint32_t y1 = cvtpk(p[10], p[11]), y3 = cvtpk(p[14], p[15]);
        swap32(y0, y2); swap32(y1, y3);    // words for k-step 1
        uint4 pw0; pw0.x = w0; pw0.y = w1; pw0.z = w2; pw0.w = w3;
        uint4 pw1; pw1.x = y0; pw1.y = y1; pw1.z = y2; pw1.w = y3;
        pf0 = __builtin_bit_cast(bf16x8_t, pw0);
        pf1 = __builtin_bit_cast(bf16x8_t, pw1);
    }

    // ---- drain: PV[NT-1] ----
#pragma unroll
    for (int dg = 0; dg < 4; ++dg) {
        Ow[dg] = MFMA32(vf0[dg], pf0, Ow[dg], 0, 0, 0);
        Ow[dg] = MFMA32(vf1[dg], pf1, Ow[dg], 0, 0, 0);
    }

    // ---- epilogue: reduce l across halves, store UNNORMALIZED partials ----
    lsum += __shfl_xor(lsum, 32, 64);
    u16t* Op = z ? Op1 : Op0;
    size_t i = (size_t)(q0 + wave * 32 + l31);
    if (hh == 0) lp[z * 32768 + i * 8 + h] = lsum;
#pragma unroll
    for (int dg = 0; dg < 4; ++dg)
#pragma unroll
        for (int g = 0; g < 4; ++g) {
            uint2 pk;
            pk.x = pk2bf(Ow[dg][g * 4 + 0], Ow[dg][g * 4 + 1]);
            pk.y = pk2bf(Ow[dg][g * 4 + 2], Ow[dg][g * 4 + 3]);
            *(uint2*)&Op[i * 1024 + h * 128 + dg * 32 + g * 8 + hh * 4] = pk;
        }
}

// ---------------- combine: Oh = (O0 + O1) / (l0 + l1), 8 bf16/thread ----------------
__global__ __launch_bounds__(256) void combine_kernel(
    const u16t* __restrict__ O0, const u16t* __restrict__ O1,
    const float* __restrict__ lp, u16t* __restrict__ out)
{
    int t = blockIdx.x * blockDim.x + threadIdx.x;
    int e = t << 3;
    int i = e >> 10, h = (e >> 7) & 7;
    float inv = 1.f / (lp[i * 8 + h] + lp[32768 + i * 8 + h]);
    uint4 a = ((const uint4*)O0)[t];
    uint4 b = ((const uint4*)O1)[t];
    uint4 r;
    r.x = pk2bf((bflo(a.x) + bflo(b.x)) * inv, (bfhi(a.x) + bfhi(b.x)) * inv);
    r.y = pk2bf((bflo(a.y) + bflo(b.y)) * inv, (bfhi(a.y) + bfhi(b.y)) * inv);
    r.z = pk2bf((bflo(a.z) + bflo(b.z)) * inv, (bfhi(a.z) + bfhi(b.z)) * inv);
    r.w = pk2bf((bflo(a.w) + bflo(b.w)) * inv, (bfhi(a.w) + bfhi(b.w)) * inv);
    ((uint4*)out)[t] = r;
}

// =====================================================================
extern "C" void kernel_launch(void* const* d_in, const int* in_sizes, int n_in,
                              void* d_out, int out_size, void* d_ws, size_t ws_size,
                              hipStream_t stream)
{
    (void)in_sizes; (void)n_in; (void)out_size; (void)ws_size;
    const float* x    = (const float*)d_in[0];   // (2,2048,1024)
    const float* ctx  = (const float*)d_in[1];   // (2,2048,768)
    const float* Wq   = (const float*)d_in[2];   // (1024,1024)
    const float* Wk   = (const float*)d_in[3];   // (768,1024)
    const float* Wv   = (const float*)d_in[4];   // (768,1024)
    const float* Wout = (const float*)d_in[5];   // (1024,1024)
    const float* bout = (const float*)d_in[6];   // (1024,)
    float* out = (float*)d_out;                  // (2,2048,1024) f32

    u16t* ws = (u16t*)d_ws;                      // ~47 MB of bf16 scratch
    u16t* x_bf   = ws;                           // 4194304
    u16t* ctx_bf = x_bf + 4194304;               // 3145728
    u16t* Wqt    = ctx_bf + 3145728;             // 1048576  [N=1024][K=1024]
    u16t* Wkt    = Wqt + 1048576;                // 786432   [1024][768]
    u16t* Wvt    = Wkt + 786432;                 // 786432
    u16t* Woutt  = Wvt + 786432;                 // 1048576
    u16t* Qh     = Woutt + 1048576;              // 4194304  [8][4096][128]
    u16t* Kh     = Qh + 4194304;                 // 4194304
    u16t* Vt     = Kh + 4194304;                 // 4194304  [8][128][4096]
    // flash-phase reuse of dead projection buffers:
    u16t* Oh   = x_bf;                           // split-0 partial, then combined O
    u16t* Ohp1 = ws + 4194304;                   // split-1 partial (over ctx_bf+Wqt, dead)
    float* lp  = (float*)(ws + 8388608);         // l partials [2][4096][8] (over Wkt, dead)

    // tau * dim^-0.5 * log2(e), folded into Q so flash uses raw exp2
    constexpr float QSCALE = 1.5f * 0.08838834764831845f * 1.4426950408889634f;

    cast2_bf16_kernel<<<7168, 256, 0, stream>>>(x, x_bf, 1048576, ctx, ctx_bf, 786432);
    transpose4_kernel<<<dim3(32, 32, 4), dim3(32, 8), 0, stream>>>(
        Wq, Wk, Wv, Wout, Wqt, Wkt, Wvt, Woutt);

    qkv_kernel<<<dim3(16, 32, 3), 256, 0, stream>>>(
        x_bf, ctx_bf, Wqt, Wkt, Wvt, Qh, Kh, Vt, QSCALE);

    // grid: x = q-block (128 rows), y = head, z = k-split; 512 blocks = 2 per CU
    flash_kernel<<<dim3(32, 8, 2), 256, 0, stream>>>(Qh, Kh, Vt, Oh, Ohp1, lp);
    combine_kernel<<<2048, 256, 0, stream>>>(Oh, Ohp1, lp, Oh);

    gemm_bf16_kernel<<<dim3(16, 32), 256, 0, stream>>>(Oh, Woutt, 1024, out, bout, 3, 1.0f);
}

// Round 9
// 234.616 us; speedup vs baseline: 1.6729x; 1.6729x over previous
//
#include <hip/hip_runtime.h>
#include <cstdint>
#include <cstddef>

typedef unsigned short u16t;
typedef __bf16 bf16x8_t __attribute__((ext_vector_type(8)));
typedef float f32x4_t __attribute__((ext_vector_type(4)));
typedef float f32x16_t __attribute__((ext_vector_type(16)));

#define MFMA_BF16 __builtin_amdgcn_mfma_f32_16x16x32_bf16
#define MFMA32    __builtin_amdgcn_mfma_f32_32x32x16_bf16

__device__ __forceinline__ u16t f2bf(float f) {
    uint32_t u = __builtin_bit_cast(uint32_t, f);
    u += 0x7fffu + ((u >> 16) & 1u);   // RNE
    return (u16t)(u >> 16);
}

__device__ __forceinline__ uint32_t pk2bf(float a, float b) {
    return (uint32_t)f2bf(a) | ((uint32_t)f2bf(b) << 16);
}

__device__ __forceinline__ float bflo(uint32_t u) {
    return __builtin_bit_cast(float, u << 16);
}
__device__ __forceinline__ float bfhi(uint32_t u) {
    return __builtin_bit_cast(float, u & 0xffff0000u);
}

__device__ __forceinline__ bf16x8_t ld_frag(const u16t* p) {
    return __builtin_bit_cast(bf16x8_t, *(const uint4*)p);
}

// single-instruction RNE pack of two f32 -> bf16x2
__device__ __forceinline__ uint32_t cvtpk(float lo, float hi) {
    uint32_t r;
    asm("v_cvt_pk_bf16_f32 %0, %1, %2" : "=v"(r) : "v"(lo), "v"(hi));
    return r;
}
// a[32:63] <-> b[0:31]  (gfx950 v_permlane32_swap_b32)
__device__ __forceinline__ void swap32(uint32_t& a, uint32_t& b) {
    asm("v_permlane32_swap_b32 %0, %1" : "+v"(a), "+v"(b));
}

// async global->LDS DMA, 16 B per lane. lds base must be wave-uniform;
// lane i deposits at lds + i*16 B. Swizzling is done on the GLOBAL address.
__device__ __forceinline__ void gl_lds16(const u16t* g, u16t* l) {
    __builtin_amdgcn_global_load_lds(
        (const __attribute__((address_space(1))) void*)g,
        (__attribute__((address_space(3))) void*)l, 16, 0, 0);
}

// ---------------- fused cast f32 -> bf16 for x and ctx, 4 elems/thread ----------------
__global__ void cast2_bf16_kernel(const float* __restrict__ s0, u16t* __restrict__ d0, int n0,
                                  const float* __restrict__ s1, u16t* __restrict__ d1, int n1) {
    int i = blockIdx.x * blockDim.x + threadIdx.x;
    const float* s; u16t* d;
    if (i < n0) { s = s0; d = d0; }
    else { i -= n0; if (i >= n1) return; s = s1; d = d1; }
    float4 v = ((const float4*)s)[i];
    uint2 o;
    o.x = pk2bf(v.x, v.y);
    o.y = pk2bf(v.z, v.w);
    ((uint2*)d)[i] = o;
}

// ---------------- fused transpose+cast of all 4 weights: W[K][1024] -> Wt[1024][K] ----
__global__ void transpose4_kernel(const float* __restrict__ Wq, const float* __restrict__ Wk,
                                  const float* __restrict__ Wv, const float* __restrict__ Wo,
                                  u16t* __restrict__ Wqt, u16t* __restrict__ Wkt,
                                  u16t* __restrict__ Wvt, u16t* __restrict__ Wot) {
    const int z = blockIdx.z;
    const float* W = z == 0 ? Wq : (z == 1 ? Wk : (z == 2 ? Wv : Wo));
    u16t* Wt      = z == 0 ? Wqt : (z == 1 ? Wkt : (z == 2 ? Wvt : Wot));
    const int K   = (z == 1 || z == 2) ? 768 : 1024;
    const int N = 1024;
    int n0 = blockIdx.x * 32, k0 = blockIdx.y * 32;
    if (k0 >= K) return;
    __shared__ float tile[32][33];
    int tx = threadIdx.x, ty = threadIdx.y;
    for (int i = ty; i < 32; i += 8)
        tile[i][tx] = W[(size_t)(k0 + i) * N + n0 + tx];
    __syncthreads();
    for (int i = ty; i < 32; i += 8)
        Wt[(size_t)(n0 + i) * K + k0 + tx] = f2bf(tile[tx][i]);
}

// ---------------- GEMM core: C = A[M][K]bf16 @ Bt[N][K]^T, tile 128x64 ----------------
// DMA double-buffer, one barrier per K-step.
// mode 0: bf16 head-split store out[(h*4096+row)*128+d] * oscale  (Q/K)
// mode 2: bf16 transposed store out[(h*128+d)*4096+row]           (V^T)
// mode 3: f32 store out[row*1024+c] + bias[c]                     (final)
__device__ __forceinline__ void gemm_core(
    const u16t* __restrict__ A, const u16t* __restrict__ Bt,
    int K, void* __restrict__ outp, const float* __restrict__ bias,
    int mode, float oscale, int bm, int bn)
{
    __shared__ __align__(16) u16t As[2][128 * 64];
    __shared__ __align__(16) u16t Bs[2][64 * 64];
    const int tid = threadIdx.x;
    const int wave = tid >> 6, lane = tid & 63;
    const int wm = wave & 1, wn = wave >> 1;
    const int quad = lane >> 4, l16 = lane & 15;

    const int l8r = lane >> 3, l8c = lane & 7;
    const int cgx = (l8c ^ l8r) * 8;

    f32x4_t acc[4][2];
#pragma unroll
    for (int i = 0; i < 4; ++i)
#pragma unroll
        for (int j = 0; j < 2; ++j) acc[i][j] = (f32x4_t){0.f, 0.f, 0.f, 0.f};

    const int nk = K >> 6;

#pragma unroll
    for (int it = 0; it < 4; ++it) {
        int rb = wave * 32 + it * 8;
        gl_lds16(&A[(size_t)(bm + rb + l8r) * K + cgx], &As[0][rb * 64]);
    }
#pragma unroll
    for (int it = 0; it < 2; ++it) {
        int rb = wave * 16 + it * 8;
        gl_lds16(&Bt[(size_t)(bn + rb + l8r) * K + cgx], &Bs[0][rb * 64]);
    }

    for (int ki = 0; ki < nk; ++ki) {
        const int buf = ki & 1;
        __syncthreads();

        if (ki + 1 < nk) {
            const int kc = (ki + 1) << 6;
#pragma unroll
            for (int it = 0; it < 4; ++it) {
                int rb = wave * 32 + it * 8;
                gl_lds16(&A[(size_t)(bm + rb + l8r) * K + kc + cgx], &As[buf ^ 1][rb * 64]);
            }
#pragma unroll
            for (int it = 0; it < 2; ++it) {
                int rb = wave * 16 + it * 8;
                gl_lds16(&Bt[(size_t)(bn + rb + l8r) * K + kc + cgx], &Bs[buf ^ 1][rb * 64]);
            }
        }

#pragma unroll
        for (int ks = 0; ks < 2; ++ks) {
            bf16x8_t af[4], bfv[2];
#pragma unroll
            for (int i = 0; i < 4; ++i) {
                int r = wm * 64 + i * 16 + l16;
                af[i] = ld_frag(&As[buf][r * 64 + (((ks * 4 + quad) ^ (r & 7)) * 8)]);
            }
#pragma unroll
            for (int j = 0; j < 2; ++j) {
                int r = wn * 32 + j * 16 + l16;
                bfv[j] = ld_frag(&Bs[buf][r * 64 + (((ks * 4 + quad) ^ (r & 7)) * 8)]);
            }
#pragma unroll
            for (int i = 0; i < 4; ++i)
#pragma unroll
                for (int j = 0; j < 2; ++j)
                    acc[i][j] = MFMA_BF16(af[i], bfv[j], acc[i][j], 0, 0, 0);
        }
    }

    if (mode == 3) {
        float* out = (float*)outp;
#pragma unroll
        for (int j = 0; j < 2; ++j) {
            int c = bn + wn * 32 + j * 16 + l16;
            float b = bias[c];
#pragma unroll
            for (int i = 0; i < 4; ++i) {
                int rb = bm + wm * 64 + i * 16 + quad * 4;
#pragma unroll
                for (int r = 0; r < 4; ++r)
                    out[(size_t)(rb + r) * 1024 + c] = acc[i][j][r] + b;
            }
        }
    } else if (mode == 2) {
        u16t* out = (u16t*)outp;
#pragma unroll
        for (int i = 0; i < 4; ++i)
#pragma unroll
            for (int j = 0; j < 2; ++j) {
                int rb = bm + wm * 64 + i * 16 + quad * 4;
                int c = bn + wn * 32 + j * 16 + l16;
                int h = c >> 7, d = c & 127;
                uint2 pk;
                pk.x = pk2bf(acc[i][j][0], acc[i][j][1]);
                pk.y = pk2bf(acc[i][j][2], acc[i][j][3]);
                *(uint2*)&out[((size_t)h * 128 + d) * 4096 + rb] = pk;
            }
    } else {
        u16t* out = (u16t*)outp;
#pragma unroll
        for (int i = 0; i < 4; ++i)
#pragma unroll
            for (int j = 0; j < 2; ++j) {
                int rb = bm + wm * 64 + i * 16 + quad * 4;
                int c = bn + wn * 32 + j * 16 + l16;
                int h = c >> 7, d = c & 127;
#pragma unroll
                for (int r = 0; r < 4; ++r)
                    out[((size_t)h * 4096 + rb + r) * 128 + d] = f2bf(acc[i][j][r] * oscale);
            }
    }
}

__global__ __launch_bounds__(256) void gemm_bf16_kernel(
    const u16t* __restrict__ A, const u16t* __restrict__ Bt,
    int K, void* __restrict__ outp, const float* __restrict__ bias,
    int mode, float oscale)
{
    gemm_core(A, Bt, K, outp, bias, mode, oscale, blockIdx.y * 128, blockIdx.x * 64);
}

// ---------------- fused Q/K/V projections: grid.z selects the GEMM ----------------
__global__ __launch_bounds__(256) void qkv_kernel(
    const u16t* __restrict__ x_bf, const u16t* __restrict__ ctx_bf,
    const u16t* __restrict__ Wqt, const u16t* __restrict__ Wkt,
    const u16t* __restrict__ Wvt,
    u16t* __restrict__ Qh, u16t* __restrict__ Kh, u16t* __restrict__ Vt,
    float qscale)
{
    const int z = blockIdx.z;
    const u16t* A  = (z == 0) ? x_bf : ctx_bf;
    const u16t* Bt = (z == 0) ? Wqt : ((z == 1) ? Wkt : Wvt);
    void* outp     = (z == 0) ? (void*)Qh : ((z == 1) ? (void*)Kh : (void*)Vt);
    const int K    = (z == 0) ? 1024 : 768;
    const int mode = (z == 2) ? 2 : 0;
    const float sc = (z == 0) ? qscale : 1.0f;
    gemm_core(A, Bt, K, outp, nullptr, mode, sc, blockIdx.y * 128, blockIdx.x * 64);
}

// ---------------- flash attention v11: v9 skeleton, KVBLK=64 (barrier amortization) ----
// v10 post-mortem: register-direct gather = 32 cache lines/instr -> 3x slower. LDS
// staging restored. v9 post-mortem: per-barrier drain+convergence (~1500 cyc) is the
// binding cost. v11: each iteration processes a 64-k tile -> 32 MFMA + 32 ds_read per
// wave-iter, HALF the barriers (33 vs 65); per-barrier stall amortized over 2x work.
// V DMA re-timed (issue V[t] at iter t, consumed by PV[t] at t+1) -> V double-buffer
// suffices. LDS: K dbuf 2x16KB + V dbuf 2x16KB = 64KB -> 2 blocks/CU.
// V rows now 128 B (8 chunks); swizzle g(r) = (r ^ (r>>3)) & 7 on deposit AND read:
// chunk distribution uniform (8 lanes / 16B group = b128 minimum) -> conflict-free.
// Deferred PV (v8-proven) kept: PV[t-1] from pf regs, independent of QK^T[t].
__global__ __launch_bounds__(256, 2) void flash_kernel(
    const u16t* __restrict__ Qh, const u16t* __restrict__ Kh,
    const u16t* __restrict__ Vtg, u16t* __restrict__ Op0,
    u16t* __restrict__ Op1, float* __restrict__ lp)
{
    extern __shared__ __align__(16) u16t smem[];   // 65536 B
    const int h = blockIdx.y;
    const int q0 = blockIdx.x * 128;
    const int z = blockIdx.z;
    const int tid = threadIdx.x;
    const int wave = tid >> 6, lane = tid & 63;
    const int l31 = lane & 31, hh = lane >> 5;
    const int NT = 32;                              // 2048 k per z-split / 64

    const u16t* Kg = Kh + (size_t)h * 4096 * 128 + (size_t)z * 2048 * 128;
    const u16t* Vg = Vtg + (size_t)h * 128 * 4096 + z * 2048;

    // ---- stage Q (128 x 128) swizzled into smem, build qf (8 frags = wave's 32 q) ----
    {
        const u16t* Qg = Qh + ((size_t)h * 4096 + q0) * 128;
#pragma unroll
        for (int it = 0; it < 8; ++it) {
            int slot = it * 256 + tid;
            int r = slot >> 4, c = slot & 15;
            uint4 v = *(const uint4*)&Qg[(size_t)r * 128 + c * 8];
            *(uint4*)&smem[r * 128 + ((c ^ (r & 15)) * 8)] = v;
        }
    }
    __syncthreads();
    bf16x8_t qf[8];
    {
        int r = wave * 32 + l31;
#pragma unroll
        for (int s = 0; s < 8; ++s)
            qf[s] = ld_frag(&smem[r * 128 + (((s * 2 + hh) ^ (r & 15)) * 8)]);
    }
    __syncthreads();   // all waves done reading Q before DMA overwrites

    // DMA roles: waves 0,1 stage K (64x128, 8 issues each), waves 2,3 stage V^T (128x64)
    const bool kRole = wave < 2;
    const int wh = wave & 1;
    const int rK = lane >> 4, cK = lane & 15;   // K: 4 rows x 16 chunks (256B rows)
    const int rV = lane >> 3, cV = lane & 7;    // V: 8 rows x 8 chunks (128B rows)

    // ---- prologue: K[0] -> kslot0 (V[0] is issued inside the loop at t=0) ----
    if (kRole) {
#pragma unroll
        for (int it = 0; it < 8; ++it) {
            int is = wh * 8 + it;
            int rowL = is * 4 + rK;
            gl_lds16(Kg + (size_t)rowL * 128 + ((cK ^ (rowL & 15)) * 8),
                     smem + is * 512);
        }
    }

    f32x16_t Ow[4];
#pragma unroll
    for (int dg = 0; dg < 4; ++dg)
#pragma unroll
        for (int r = 0; r < 16; ++r) Ow[dg][r] = 0.f;

    float lsum = 0.f;
    const int swzk = l31 & 15;
    bf16x8_t pf[4];            // P of tile t-1 (k-slices 0..3), consumed at iter t

    for (int t = 0; t <= NT; ++t) {
        __syncthreads();   // drains each wave's own DMA: K[t] (issued t-1), V[t-1] (issued t-1)

        // ---- issue DMA: V-role stages V[t] (used at t+1); K-role stages K[t+1] ----
        if (kRole) {
            if (t + 1 < NT) {
                const int j0 = (t + 1) * 64;
                u16t* kd = smem + ((t + 1) & 1) * 8192;
#pragma unroll
                for (int it = 0; it < 8; ++it) {
                    int is = wh * 8 + it;
                    int rowL = is * 4 + rK;
                    gl_lds16(Kg + (size_t)(j0 + rowL) * 128 + ((cK ^ (rowL & 15)) * 8),
                             kd + is * 512);
                }
            }
        } else {
            if (t < NT) {
                const int j0 = t * 64;
                u16t* vd = smem + 16384 + (t & 1) * 8192;
#pragma unroll
                for (int it = 0; it < 8; ++it) {
                    int is = wh * 8 + it;
                    int rowL = is * 8 + rV;
                    gl_lds16(Vg + (size_t)rowL * 4096 + j0 + ((cV ^ ((rowL ^ (rowL >> 3)) & 7)) * 8),
                             vd + is * 512);
                }
            }
        }

        __builtin_amdgcn_s_setprio(1);
        // ---- QK^T[t]: two 32x32 S-tiles (k 0-31, 32-63), K-frags row l31 / 32+l31 ----
        f32x16_t St0, St1;
#pragma unroll
        for (int r = 0; r < 16; ++r) { St0[r] = 0.f; St1[r] = 0.f; }
        if (t < NT) {
            const u16t* kb = smem + (t & 1) * 8192;
#pragma unroll
            for (int s = 0; s < 8; ++s) {
                int ch = ((s * 2 + hh) ^ swzk) * 8;
                bf16x8_t k0 = ld_frag(&kb[l31 * 128 + ch]);
                bf16x8_t k1 = ld_frag(&kb[(32 + l31) * 128 + ch]);
                St0 = MFMA32(k0, qf[s], St0, 0, 0, 0);
                St1 = MFMA32(k1, qf[s], St1, 0, 0, 0);
            }
        }
        // ---- PV[t-1]: V^T (vslot (t-1)&1) x pf (registers from last iter) ----
        if (t >= 1) {
            const u16t* vb = smem + 16384 + ((t - 1) & 1) * 8192;
#pragma unroll
            for (int dg = 0; dg < 4; ++dg) {
                int rv = dg * 32 + l31;
                int gsw = (rv ^ (rv >> 3)) & 7;
#pragma unroll
                for (int sl = 0; sl < 4; ++sl) {
                    bf16x8_t vf = ld_frag(&vb[rv * 64 + (((sl * 2 + hh) ^ gsw) * 8)]);
                    Ow[dg] = MFMA32(vf, pf[sl], Ow[dg], 0, 0, 0);
                }
            }
        }
        __builtin_amdgcn_s_setprio(0);

        // ---- softmax[t] -> pf[0..3] for next iter's PV ----
        if (t < NT) {
#pragma unroll
            for (int half = 0; half < 2; ++half) {
                float p[16];
#pragma unroll
                for (int r = 0; r < 16; ++r)
                    p[r] = __builtin_amdgcn_exp2f(half ? St1[r] : St0[r]);
                lsum += ((((p[0] + p[1]) + (p[2] + p[3])) + ((p[4] + p[5]) + (p[6] + p[7])))
                      + (((p[8] + p[9]) + (p[10] + p[11])) + ((p[12] + p[13]) + (p[14] + p[15]))));
                uint32_t w0 = cvtpk(p[0], p[1]),   w2 = cvtpk(p[4], p[5]);
                uint32_t w1 = cvtpk(p[2], p[3]),   w3 = cvtpk(p[6], p[7]);
                swap32(w0, w2); swap32(w1, w3);    // words for even k-slice
                uint32_t y0 = cvtpk(p[8], p[9]),   y2 = cvtpk(p[12], p[13]);
                uint32_t y1 = cvtpk(p[10], p[11]), y3 = cvtpk(p[14], p[15]);
                swap32(y0, y2); swap32(y1, y3);    // words for odd k-slice
                uint4 pw0; pw0.x = w0; pw0.y = w1; pw0.z = w2; pw0.w = w3;
                uint4 pw1; pw1.x = y0; pw1.y = y1; pw1.z = y2; pw1.w = y3;
                pf[half * 2 + 0] = __builtin_bit_cast(bf16x8_t, pw0);
                pf[half * 2 + 1] = __builtin_bit_cast(bf16x8_t, pw1);
            }
        }
    }

    // ---- epilogue: reduce l across halves, store UNNORMALIZED partials ----
    lsum += __shfl_xor(lsum, 32, 64);
    u16t* Op = z ? Op1 : Op0;
    size_t i = (size_t)(q0 + wave * 32 + l31);
    if (hh == 0) lp[z * 32768 + i * 8 + h] = lsum;
#pragma unroll
    for (int dg = 0; dg < 4; ++dg)
#pragma unroll
        for (int g = 0; g < 4; ++g) {
            uint2 pk;
            pk.x = pk2bf(Ow[dg][g * 4 + 0], Ow[dg][g * 4 + 1]);
            pk.y = pk2bf(Ow[dg][g * 4 + 2], Ow[dg][g * 4 + 3]);
            *(uint2*)&Op[i * 1024 + h * 128 + dg * 32 + g * 8 + hh * 4] = pk;
        }
}

// ---------------- combine: Oh = (O0 + O1) / (l0 + l1), 8 bf16/thread ----------------
__global__ __launch_bounds__(256) void combine_kernel(
    const u16t* __restrict__ O0, const u16t* __restrict__ O1,
    const float* __restrict__ lp, u16t* __restrict__ out)
{
    int t = blockIdx.x * blockDim.x + threadIdx.x;
    int e = t << 3;
    int i = e >> 10, h = (e >> 7) & 7;
    float inv = 1.f / (lp[i * 8 + h] + lp[32768 + i * 8 + h]);
    uint4 a = ((const uint4*)O0)[t];
    uint4 b = ((const uint4*)O1)[t];
    uint4 r;
    r.x = pk2bf((bflo(a.x) + bflo(b.x)) * inv, (bfhi(a.x) + bfhi(b.x)) * inv);
    r.y = pk2bf((bflo(a.y) + bflo(b.y)) * inv, (bfhi(a.y) + bfhi(b.y)) * inv);
    r.z = pk2bf((bflo(a.z) + bflo(b.z)) * inv, (bfhi(a.z) + bfhi(b.z)) * inv);
    r.w = pk2bf((bflo(a.w) + bflo(b.w)) * inv, (bfhi(a.w) + bfhi(b.w)) * inv);
    ((uint4*)out)[t] = r;
}

// =====================================================================
extern "C" void kernel_launch(void* const* d_in, const int* in_sizes, int n_in,
                              void* d_out, int out_size, void* d_ws, size_t ws_size,
                              hipStream_t stream)
{
    (void)in_sizes; (void)n_in; (void)out_size; (void)ws_size;
    const float* x    = (const float*)d_in[0];   // (2,2048,1024)
    const float* ctx  = (const float*)d_in[1];   // (2,2048,768)
    const float* Wq   = (const float*)d_in[2];   // (1024,1024)
    const float* Wk   = (const float*)d_in[3];   // (768,1024)
    const float* Wv   = (const float*)d_in[4];   // (768,1024)
    const float* Wout = (const float*)d_in[5];   // (1024,1024)
    const float* bout = (const float*)d_in[6];   // (1024,)
    float* out = (float*)d_out;                  // (2,2048,1024) f32

    u16t* ws = (u16t*)d_ws;                      // ~47 MB of bf16 scratch
    u16t* x_bf   = ws;                           // 4194304
    u16t* ctx_bf = x_bf + 4194304;               // 3145728
    u16t* Wqt    = ctx_bf + 3145728;             // 1048576  [N=1024][K=1024]
    u16t* Wkt    = Wqt + 1048576;                // 786432   [1024][768]
    u16t* Wvt    = Wkt + 786432;                 // 786432
    u16t* Woutt  = Wvt + 786432;                 // 1048576
    u16t* Qh     = Woutt + 1048576;              // 4194304  [8][4096][128]
    u16t* Kh     = Qh + 4194304;                 // 4194304
    u16t* Vt     = Kh + 4194304;                 // 4194304  [8][128][4096]
    // flash-phase reuse of dead projection buffers:
    u16t* Oh   = x_bf;                           // split-0 partial, then combined O
    u16t* Ohp1 = ws + 4194304;                   // split-1 partial (over ctx_bf+Wqt, dead)
    float* lp  = (float*)(ws + 8388608);         // l partials [2][4096][8] (over Wkt, dead)

    // tau * dim^-0.5 * log2(e), folded into Q so flash uses raw exp2
    constexpr float QSCALE = 1.5f * 0.08838834764831845f * 1.4426950408889634f;

    (void)hipFuncSetAttribute((const void*)flash_kernel,
                              hipFuncAttributeMaxDynamicSharedMemorySize, 65536);

    cast2_bf16_kernel<<<7168, 256, 0, stream>>>(x, x_bf, 1048576, ctx, ctx_bf, 786432);
    transpose4_kernel<<<dim3(32, 32, 4), dim3(32, 8), 0, stream>>>(
        Wq, Wk, Wv, Wout, Wqt, Wkt, Wvt, Woutt);

    qkv_kernel<<<dim3(16, 32, 3), 256, 0, stream>>>(
        x_bf, ctx_bf, Wqt, Wkt, Wvt, Qh, Kh, Vt, QSCALE);

    // grid: x = q-block (128 rows), y = head, z = k-split; 512 blocks = 2 per CU
    flash_kernel<<<dim3(32, 8, 2), 256, 65536, stream>>>(Qh, Kh, Vt, Oh, Ohp1, lp);
    combine_kernel<<<2048, 256, 0, stream>>>(Oh, Ohp1, lp, Oh);

    gemm_bf16_kernel<<<dim3(16, 32), 256, 0, stream>>>(Oh, Woutt, 1024, out, bout, 3, 1.0f);
}

// Round 10
// 229.599 us; speedup vs baseline: 1.7094x; 1.0219x over previous
//
#include <hip/hip_runtime.h>
#include <cstdint>
#include <cstddef>

typedef unsigned short u16t;
typedef __bf16 bf16x8_t __attribute__((ext_vector_type(8)));
typedef float f32x4_t __attribute__((ext_vector_type(4)));
typedef float f32x16_t __attribute__((ext_vector_type(16)));

#define MFMA_BF16 __builtin_amdgcn_mfma_f32_16x16x32_bf16
#define MFMA32    __builtin_amdgcn_mfma_f32_32x32x16_bf16

__device__ __forceinline__ u16t f2bf(float f) {
    uint32_t u = __builtin_bit_cast(uint32_t, f);
    u += 0x7fffu + ((u >> 16) & 1u);   // RNE
    return (u16t)(u >> 16);
}

__device__ __forceinline__ uint32_t pk2bf(float a, float b) {
    return (uint32_t)f2bf(a) | ((uint32_t)f2bf(b) << 16);
}

__device__ __forceinline__ float bflo(uint32_t u) {
    return __builtin_bit_cast(float, u << 16);
}
__device__ __forceinline__ float bfhi(uint32_t u) {
    return __builtin_bit_cast(float, u & 0xffff0000u);
}

__device__ __forceinline__ bf16x8_t ld_frag(const u16t* p) {
    return __builtin_bit_cast(bf16x8_t, *(const uint4*)p);
}

// single-instruction RNE pack of two f32 -> bf16x2
__device__ __forceinline__ uint32_t cvtpk(float lo, float hi) {
    uint32_t r;
    asm("v_cvt_pk_bf16_f32 %0, %1, %2" : "=v"(r) : "v"(lo), "v"(hi));
    return r;
}
// a[32:63] <-> b[0:31]  (gfx950 v_permlane32_swap_b32)
__device__ __forceinline__ void swap32(uint32_t& a, uint32_t& b) {
    asm("v_permlane32_swap_b32 %0, %1" : "+v"(a), "+v"(b));
}

// async global->LDS DMA, 16 B per lane. lds base must be wave-uniform;
// lane i deposits at lds + i*16 B. Swizzling is done on the GLOBAL address.
__device__ __forceinline__ void gl_lds16(const u16t* g, u16t* l) {
    __builtin_amdgcn_global_load_lds(
        (const __attribute__((address_space(1))) void*)g,
        (__attribute__((address_space(3))) void*)l, 16, 0, 0);
}

// ---------------- fused cast f32 -> bf16 for x and ctx, 4 elems/thread ----------------
__global__ void cast2_bf16_kernel(const float* __restrict__ s0, u16t* __restrict__ d0, int n0,
                                  const float* __restrict__ s1, u16t* __restrict__ d1, int n1) {
    int i = blockIdx.x * blockDim.x + threadIdx.x;
    const float* s; u16t* d;
    if (i < n0) { s = s0; d = d0; }
    else { i -= n0; if (i >= n1) return; s = s1; d = d1; }
    float4 v = ((const float4*)s)[i];
    uint2 o;
    o.x = pk2bf(v.x, v.y);
    o.y = pk2bf(v.z, v.w);
    ((uint2*)d)[i] = o;
}

// ---------------- fused transpose+cast of all 4 weights: W[K][1024] -> Wt[1024][K] ----
__global__ void transpose4_kernel(const float* __restrict__ Wq, const float* __restrict__ Wk,
                                  const float* __restrict__ Wv, const float* __restrict__ Wo,
                                  u16t* __restrict__ Wqt, u16t* __restrict__ Wkt,
                                  u16t* __restrict__ Wvt, u16t* __restrict__ Wot) {
    const int z = blockIdx.z;
    const float* W = z == 0 ? Wq : (z == 1 ? Wk : (z == 2 ? Wv : Wo));
    u16t* Wt      = z == 0 ? Wqt : (z == 1 ? Wkt : (z == 2 ? Wvt : Wot));
    const int K   = (z == 1 || z == 2) ? 768 : 1024;
    const int N = 1024;
    int n0 = blockIdx.x * 32, k0 = blockIdx.y * 32;
    if (k0 >= K) return;
    __shared__ float tile[32][33];
    int tx = threadIdx.x, ty = threadIdx.y;
    for (int i = ty; i < 32; i += 8)
        tile[i][tx] = W[(size_t)(k0 + i) * N + n0 + tx];
    __syncthreads();
    for (int i = ty; i < 32; i += 8)
        Wt[(size_t)(n0 + i) * K + k0 + tx] = f2bf(tile[tx][i]);
}

// ---------------- old GEMM core (kept for the final projection, mode 3) ----------------
__device__ __forceinline__ void gemm_core(
    const u16t* __restrict__ A, const u16t* __restrict__ Bt,
    int K, void* __restrict__ outp, const float* __restrict__ bias,
    int mode, float oscale, int bm, int bn)
{
    __shared__ __align__(16) u16t As[2][128 * 64];
    __shared__ __align__(16) u16t Bs[2][64 * 64];
    const int tid = threadIdx.x;
    const int wave = tid >> 6, lane = tid & 63;
    const int wm = wave & 1, wn = wave >> 1;
    const int quad = lane >> 4, l16 = lane & 15;

    const int l8r = lane >> 3, l8c = lane & 7;
    const int cgx = (l8c ^ l8r) * 8;

    f32x4_t acc[4][2];
#pragma unroll
    for (int i = 0; i < 4; ++i)
#pragma unroll
        for (int j = 0; j < 2; ++j) acc[i][j] = (f32x4_t){0.f, 0.f, 0.f, 0.f};

    const int nk = K >> 6;

#pragma unroll
    for (int it = 0; it < 4; ++it) {
        int rb = wave * 32 + it * 8;
        gl_lds16(&A[(size_t)(bm + rb + l8r) * K + cgx], &As[0][rb * 64]);
    }
#pragma unroll
    for (int it = 0; it < 2; ++it) {
        int rb = wave * 16 + it * 8;
        gl_lds16(&Bt[(size_t)(bn + rb + l8r) * K + cgx], &Bs[0][rb * 64]);
    }

    for (int ki = 0; ki < nk; ++ki) {
        const int buf = ki & 1;
        __syncthreads();

        if (ki + 1 < nk) {
            const int kc = (ki + 1) << 6;
#pragma unroll
            for (int it = 0; it < 4; ++it) {
                int rb = wave * 32 + it * 8;
                gl_lds16(&A[(size_t)(bm + rb + l8r) * K + kc + cgx], &As[buf ^ 1][rb * 64]);
            }
#pragma unroll
            for (int it = 0; it < 2; ++it) {
                int rb = wave * 16 + it * 8;
                gl_lds16(&Bt[(size_t)(bn + rb + l8r) * K + kc + cgx], &Bs[buf ^ 1][rb * 64]);
            }
        }

#pragma unroll
        for (int ks = 0; ks < 2; ++ks) {
            bf16x8_t af[4], bfv[2];
#pragma unroll
            for (int i = 0; i < 4; ++i) {
                int r = wm * 64 + i * 16 + l16;
                af[i] = ld_frag(&As[buf][r * 64 + (((ks * 4 + quad) ^ (r & 7)) * 8)]);
            }
#pragma unroll
            for (int j = 0; j < 2; ++j) {
                int r = wn * 32 + j * 16 + l16;
                bfv[j] = ld_frag(&Bs[buf][r * 64 + (((ks * 4 + quad) ^ (r & 7)) * 8)]);
            }
#pragma unroll
            for (int i = 0; i < 4; ++i)
#pragma unroll
                for (int j = 0; j < 2; ++j)
                    acc[i][j] = MFMA_BF16(af[i], bfv[j], acc[i][j], 0, 0, 0);
        }
    }

    if (mode == 3) {
        float* out = (float*)outp;
#pragma unroll
        for (int j = 0; j < 2; ++j) {
            int c = bn + wn * 32 + j * 16 + l16;
            float b = bias[c];
#pragma unroll
            for (int i = 0; i < 4; ++i) {
                int rb = bm + wm * 64 + i * 16 + quad * 4;
#pragma unroll
                for (int r = 0; r < 4; ++r)
                    out[(size_t)(rb + r) * 1024 + c] = acc[i][j][r] + b;
            }
        }
    }
}

__global__ __launch_bounds__(256) void gemm_bf16_kernel(
    const u16t* __restrict__ A, const u16t* __restrict__ Bt,
    int K, void* __restrict__ outp, const float* __restrict__ bias,
    int mode, float oscale)
{
    gemm_core(A, Bt, K, outp, bias, mode, oscale, blockIdx.y * 128, blockIdx.x * 64);
}

// ---------------- qkv128: 128x128-tile MFMA32 QKV projections ----------------
// v11-flash-proven machinery transplanted to GEMM: BK=64, one barrier/K-step,
// wave-role DMA staging (waves 0,1 -> A panel; 2,3 -> B panel), rows 128 B with
// swizzle g(r) = (r ^ (r>>3)) & 7 on deposit AND read (measured 0 conflicts in v11).
// 4 waves (2x2), each computes 64x64 via 2x2 MFMA32 tiles, acc = 4 x f32x16.
// Per K-step/wave: 16 ds_read_b128 : 16 MFMA32 (32.8 kFLOP/read, 1.5x old core;
// 524 kFLOP/barrier/block, 2x old). N-tile 128 = exactly one head: h = blockIdx.x.
// LDS 64 KB (A 2x16KB + B 2x16KB) -> 2 blocks/CU. Grid (8,32,3) = 768 blocks.
__global__ __launch_bounds__(256, 2) void qkv128_kernel(
    const u16t* __restrict__ x_bf, const u16t* __restrict__ ctx_bf,
    const u16t* __restrict__ Wqt, const u16t* __restrict__ Wkt,
    const u16t* __restrict__ Wvt,
    u16t* __restrict__ Qh, u16t* __restrict__ Kh, u16t* __restrict__ Vt,
    float qscale)
{
    extern __shared__ __align__(16) u16t sm[];  // u16 units: A[2][8192] at 0, B[2][8192] at 16384
    const int z = blockIdx.z;
    const u16t* A  = (z == 0) ? x_bf : ctx_bf;
    const u16t* Bt = (z == 0) ? Wqt : ((z == 1) ? Wkt : Wvt);
    const int K    = (z == 0) ? 1024 : 768;
    const float sc = (z == 0) ? qscale : 1.0f;
    const int m0 = blockIdx.y * 128;
    const int h  = blockIdx.x;                  // n0 = h*128

    const int tid = threadIdx.x;
    const int wave = tid >> 6, lane = tid & 63;
    const int l31 = lane & 31, hh = lane >> 5;
    const int wm = wave & 1, wn = wave >> 1;
    const bool aRole = wave < 2;
    const int wh = wave & 1;
    const int rS = lane >> 3, cS = lane & 7;    // staging: 8 rows x 8 chunks per issue

    const int nk = K >> 6;
    const u16t* G  = aRole ? A : Bt;
    const int base = aRole ? m0 : h * 128;
    u16t* dstb     = sm + (aRole ? 0 : 16384);

    // ---- prologue: stage A[*][0:64], B[*][0:64] into buf 0 ----
#pragma unroll
    for (int it = 0; it < 8; ++it) {
        int is = wh * 8 + it;
        int rowL = is * 8 + rS;
        gl_lds16(&G[(size_t)(base + rowL) * K + ((cS ^ ((rowL ^ (rowL >> 3)) & 7)) * 8)],
                 dstb + is * 512);
    }

    f32x16_t acc[2][2];
#pragma unroll
    for (int i = 0; i < 2; ++i)
#pragma unroll
        for (int j = 0; j < 2; ++j)
#pragma unroll
            for (int r = 0; r < 16; ++r) acc[i][j][r] = 0.f;

    for (int ki = 0; ki < nk; ++ki) {
        const int buf = ki & 1;
        __syncthreads();

        if (ki + 1 < nk) {
            const int kc = (ki + 1) << 6;
            u16t* dst = dstb + (buf ^ 1) * 8192;
#pragma unroll
            for (int it = 0; it < 8; ++it) {
                int is = wh * 8 + it;
                int rowL = is * 8 + rS;
                gl_lds16(&G[(size_t)(base + rowL) * K + kc + ((cS ^ ((rowL ^ (rowL >> 3)) & 7)) * 8)],
                         dst + is * 512);
            }
        }

        const u16t* As = sm + buf * 8192;
        const u16t* Bs = sm + 16384 + buf * 8192;
        __builtin_amdgcn_s_setprio(1);
#pragma unroll
        for (int s = 0; s < 4; ++s) {
            bf16x8_t af[2], bfr[2];
#pragma unroll
            for (int i = 0; i < 2; ++i) {
                int r = wm * 64 + i * 32 + l31;
                af[i] = ld_frag(&As[r * 64 + (((s * 2 + hh) ^ ((r ^ (r >> 3)) & 7)) * 8)]);
            }
#pragma unroll
            for (int j = 0; j < 2; ++j) {
                int r = wn * 64 + j * 32 + l31;
                bfr[j] = ld_frag(&Bs[r * 64 + (((s * 2 + hh) ^ ((r ^ (r >> 3)) & 7)) * 8)]);
            }
#pragma unroll
            for (int i = 0; i < 2; ++i)
#pragma unroll
                for (int j = 0; j < 2; ++j)
                    acc[i][j] = MFMA32(af[i], bfr[j], acc[i][j], 0, 0, 0);
        }
        __builtin_amdgcn_s_setprio(0);
    }

    // ---- epilogue (MFMA32 C/D: col = l31, row = (g&3) + 8*(g>>2) + 4*hh) ----
    if (z != 2) {
        // head-split store: out[(h*4096 + m)*128 + d] = bf16(acc * sc)
        u16t* out = (z == 0) ? Qh : Kh;
#pragma unroll
        for (int i = 0; i < 2; ++i)
#pragma unroll
            for (int j = 0; j < 2; ++j) {
                int d = wn * 64 + j * 32 + l31;
#pragma unroll
                for (int g = 0; g < 16; ++g) {
                    int m = m0 + wm * 64 + i * 32 + (g & 3) + 8 * (g >> 2) + 4 * hh;
                    out[((size_t)h * 4096 + m) * 128 + d] = f2bf(acc[i][j][g] * sc);
                }
            }
    } else {
        // V^T store: out[(h*128 + d)*4096 + m], 4 consecutive m per reg-quad
#pragma unroll
        for (int i = 0; i < 2; ++i)
#pragma unroll
            for (int j = 0; j < 2; ++j) {
                int d = wn * 64 + j * 32 + l31;
                size_t vb = ((size_t)h * 128 + d) * 4096 + m0 + wm * 64 + i * 32;
#pragma unroll
                for (int gq = 0; gq < 4; ++gq) {
                    uint2 pk;
                    pk.x = pk2bf(acc[i][j][gq * 4 + 0], acc[i][j][gq * 4 + 1]);
                    pk.y = pk2bf(acc[i][j][gq * 4 + 2], acc[i][j][gq * 4 + 3]);
                    *(uint2*)&Vt[vb + gq * 8 + 4 * hh] = pk;
                }
            }
    }
}

// ---------------- flash attention v11 (verbatim; proven 78.7 us, 0 conflicts) ----------------
__global__ __launch_bounds__(256, 2) void flash_kernel(
    const u16t* __restrict__ Qh, const u16t* __restrict__ Kh,
    const u16t* __restrict__ Vtg, u16t* __restrict__ Op0,
    u16t* __restrict__ Op1, float* __restrict__ lp)
{
    extern __shared__ __align__(16) u16t smem[];   // 65536 B
    const int h = blockIdx.y;
    const int q0 = blockIdx.x * 128;
    const int z = blockIdx.z;
    const int tid = threadIdx.x;
    const int wave = tid >> 6, lane = tid & 63;
    const int l31 = lane & 31, hh = lane >> 5;
    const int NT = 32;                              // 2048 k per z-split / 64

    const u16t* Kg = Kh + (size_t)h * 4096 * 128 + (size_t)z * 2048 * 128;
    const u16t* Vg = Vtg + (size_t)h * 128 * 4096 + z * 2048;

    // ---- stage Q (128 x 128) swizzled into smem, build qf (8 frags = wave's 32 q) ----
    {
        const u16t* Qg = Qh + ((size_t)h * 4096 + q0) * 128;
#pragma unroll
        for (int it = 0; it < 8; ++it) {
            int slot = it * 256 + tid;
            int r = slot >> 4, c = slot & 15;
            uint4 v = *(const uint4*)&Qg[(size_t)r * 128 + c * 8];
            *(uint4*)&smem[r * 128 + ((c ^ (r & 15)) * 8)] = v;
        }
    }
    __syncthreads();
    bf16x8_t qf[8];
    {
        int r = wave * 32 + l31;
#pragma unroll
        for (int s = 0; s < 8; ++s)
            qf[s] = ld_frag(&smem[r * 128 + (((s * 2 + hh) ^ (r & 15)) * 8)]);
    }
    __syncthreads();   // all waves done reading Q before DMA overwrites

    // DMA roles: waves 0,1 stage K (64x128, 8 issues each), waves 2,3 stage V^T (128x64)
    const bool kRole = wave < 2;
    const int wh = wave & 1;
    const int rK = lane >> 4, cK = lane & 15;   // K: 4 rows x 16 chunks (256B rows)
    const int rV = lane >> 3, cV = lane & 7;    // V: 8 rows x 8 chunks (128B rows)

    // ---- prologue: K[0] -> kslot0 (V[0] is issued inside the loop at t=0) ----
    if (kRole) {
#pragma unroll
        for (int it = 0; it < 8; ++it) {
            int is = wh * 8 + it;
            int rowL = is * 4 + rK;
            gl_lds16(Kg + (size_t)rowL * 128 + ((cK ^ (rowL & 15)) * 8),
                     smem + is * 512);
        }
    }

    f32x16_t Ow[4];
#pragma unroll
    for (int dg = 0; dg < 4; ++dg)
#pragma unroll
        for (int r = 0; r < 16; ++r) Ow[dg][r] = 0.f;

    float lsum = 0.f;
    const int swzk = l31 & 15;
    bf16x8_t pf[4];            // P of tile t-1 (k-slices 0..3), consumed at iter t

    for (int t = 0; t <= NT; ++t) {
        __syncthreads();   // drains each wave's own DMA: K[t] (issued t-1), V[t-1] (issued t-1)

        // ---- issue DMA: V-role stages V[t] (used at t+1); K-role stages K[t+1] ----
        if (kRole) {
            if (t + 1 < NT) {
                const int j0 = (t + 1) * 64;
                u16t* kd = smem + ((t + 1) & 1) * 8192;
#pragma unroll
                for (int it = 0; it < 8; ++it) {
                    int is = wh * 8 + it;
                    int rowL = is * 4 + rK;
                    gl_lds16(Kg + (size_t)(j0 + rowL) * 128 + ((cK ^ (rowL & 15)) * 8),
                             kd + is * 512);
                }
            }
        } else {
            if (t < NT) {
                const int j0 = t * 64;
                u16t* vd = smem + 16384 + (t & 1) * 8192;
#pragma unroll
                for (int it = 0; it < 8; ++it) {
                    int is = wh * 8 + it;
                    int rowL = is * 8 + rV;
                    gl_lds16(Vg + (size_t)rowL * 4096 + j0 + ((cV ^ ((rowL ^ (rowL >> 3)) & 7)) * 8),
                             vd + is * 512);
                }
            }
        }

        __builtin_amdgcn_s_setprio(1);
        // ---- QK^T[t]: two 32x32 S-tiles (k 0-31, 32-63), K-frags row l31 / 32+l31 ----
        f32x16_t St0, St1;
#pragma unroll
        for (int r = 0; r < 16; ++r) { St0[r] = 0.f; St1[r] = 0.f; }
        if (t < NT) {
            const u16t* kb = smem + (t & 1) * 8192;
#pragma unroll
            for (int s = 0; s < 8; ++s) {
                int ch = ((s * 2 + hh) ^ swzk) * 8;
                bf16x8_t k0 = ld_frag(&kb[l31 * 128 + ch]);
                bf16x8_t k1 = ld_frag(&kb[(32 + l31) * 128 + ch]);
                St0 = MFMA32(k0, qf[s], St0, 0, 0, 0);
                St1 = MFMA32(k1, qf[s], St1, 0, 0, 0);
            }
        }
        // ---- PV[t-1]: V^T (vslot (t-1)&1) x pf (registers from last iter) ----
        if (t >= 1) {
            const u16t* vb = smem + 16384 + ((t - 1) & 1) * 8192;
#pragma unroll
            for (int dg = 0; dg < 4; ++dg) {
                int rv = dg * 32 + l31;
                int gsw = (rv ^ (rv >> 3)) & 7;
#pragma unroll
                for (int sl = 0; sl < 4; ++sl) {
                    bf16x8_t vf = ld_frag(&vb[rv * 64 + (((sl * 2 + hh) ^ gsw) * 8)]);
                    Ow[dg] = MFMA32(vf, pf[sl], Ow[dg], 0, 0, 0);
                }
            }
        }
        __builtin_amdgcn_s_setprio(0);

        // ---- softmax[t] -> pf[0..3] for next iter's PV ----
        if (t < NT) {
#pragma unroll
            for (int half = 0; half < 2; ++half) {
                float p[16];
#pragma unroll
                for (int r = 0; r < 16; ++r)
                    p[r] = __builtin_amdgcn_exp2f(half ? St1[r] : St0[r]);
                lsum += ((((p[0] + p[1]) + (p[2] + p[3])) + ((p[4] + p[5]) + (p[6] + p[7])))
                      + (((p[8] + p[9]) + (p[10] + p[11])) + ((p[12] + p[13]) + (p[14] + p[15]))));
                uint32_t w0 = cvtpk(p[0], p[1]),   w2 = cvtpk(p[4], p[5]);
                uint32_t w1 = cvtpk(p[2], p[3]),   w3 = cvtpk(p[6], p[7]);
                swap32(w0, w2); swap32(w1, w3);    // words for even k-slice
                uint32_t y0 = cvtpk(p[8], p[9]),   y2 = cvtpk(p[12], p[13]);
                uint32_t y1 = cvtpk(p[10], p[11]), y3 = cvtpk(p[14], p[15]);
                swap32(y0, y2); swap32(y1, y3);    // words for odd k-slice
                uint4 pw0; pw0.x = w0; pw0.y = w1; pw0.z = w2; pw0.w = w3;
                uint4 pw1; pw1.x = y0; pw1.y = y1; pw1.z = y2; pw1.w = y3;
                pf[half * 2 + 0] = __builtin_bit_cast(bf16x8_t, pw0);
                pf[half * 2 + 1] = __builtin_bit_cast(bf16x8_t, pw1);
            }
        }
    }

    // ---- epilogue: reduce l across halves, store UNNORMALIZED partials ----
    lsum += __shfl_xor(lsum, 32, 64);
    u16t* Op = z ? Op1 : Op0;
    size_t i = (size_t)(q0 + wave * 32 + l31);
    if (hh == 0) lp[z * 32768 + i * 8 + h] = lsum;
#pragma unroll
    for (int dg = 0; dg < 4; ++dg)
#pragma unroll
        for (int g = 0; g < 4; ++g) {
            uint2 pk;
            pk.x = pk2bf(Ow[dg][g * 4 + 0], Ow[dg][g * 4 + 1]);
            pk.y = pk2bf(Ow[dg][g * 4 + 2], Ow[dg][g * 4 + 3]);
            *(uint2*)&Op[i * 1024 + h * 128 + dg * 32 + g * 8 + hh * 4] = pk;
        }
}

// ---------------- combine: Oh = (O0 + O1) / (l0 + l1), 8 bf16/thread ----------------
__global__ __launch_bounds__(256) void combine_kernel(
    const u16t* __restrict__ O0, const u16t* __restrict__ O1,
    const float* __restrict__ lp, u16t* __restrict__ out)
{
    int t = blockIdx.x * blockDim.x + threadIdx.x;
    int e = t << 3;
    int i = e >> 10, h = (e >> 7) & 7;
    float inv = 1.f / (lp[i * 8 + h] + lp[32768 + i * 8 + h]);
    uint4 a = ((const uint4*)O0)[t];
    uint4 b = ((const uint4*)O1)[t];
    uint4 r;
    r.x = pk2bf((bflo(a.x) + bflo(b.x)) * inv, (bfhi(a.x) + bfhi(b.x)) * inv);
    r.y = pk2bf((bflo(a.y) + bflo(b.y)) * inv, (bfhi(a.y) + bfhi(b.y)) * inv);
    r.z = pk2bf((bflo(a.z) + bflo(b.z)) * inv, (bfhi(a.z) + bfhi(b.z)) * inv);
    r.w = pk2bf((bflo(a.w) + bflo(b.w)) * inv, (bfhi(a.w) + bfhi(b.w)) * inv);
    ((uint4*)out)[t] = r;
}

// =====================================================================
extern "C" void kernel_launch(void* const* d_in, const int* in_sizes, int n_in,
                              void* d_out, int out_size, void* d_ws, size_t ws_size,
                              hipStream_t stream)
{
    (void)in_sizes; (void)n_in; (void)out_size; (void)ws_size;
    const float* x    = (const float*)d_in[0];   // (2,2048,1024)
    const float* ctx  = (const float*)d_in[1];   // (2,2048,768)
    const float* Wq   = (const float*)d_in[2];   // (1024,1024)
    const float* Wk   = (const float*)d_in[3];   // (768,1024)
    const float* Wv   = (const float*)d_in[4];   // (768,1024)
    const float* Wout = (const float*)d_in[5];   // (1024,1024)
    const float* bout = (const float*)d_in[6];   // (1024,)
    float* out = (float*)d_out;                  // (2,2048,1024) f32

    u16t* ws = (u16t*)d_ws;                      // ~47 MB of bf16 scratch
    u16t* x_bf   = ws;                           // 4194304
    u16t* ctx_bf = x_bf + 4194304;               // 3145728
    u16t* Wqt    = ctx_bf + 3145728;             // 1048576  [N=1024][K=1024]
    u16t* Wkt    = Wqt + 1048576;                // 786432   [1024][768]
    u16t* Wvt    = Wkt + 786432;                 // 786432
    u16t* Woutt  = Wvt + 786432;                 // 1048576
    u16t* Qh     = Woutt + 1048576;              // 4194304  [8][4096][128]
    u16t* Kh     = Qh + 4194304;                 // 4194304
    u16t* Vt     = Kh + 4194304;                 // 4194304  [8][128][4096]
    // flash-phase reuse of dead projection buffers:
    u16t* Oh   = x_bf;                           // split-0 partial, then combined O
    u16t* Ohp1 = ws + 4194304;                   // split-1 partial (over ctx_bf+Wqt, dead)
    float* lp  = (float*)(ws + 8388608);         // l partials [2][4096][8] (over Wkt, dead)

    // tau * dim^-0.5 * log2(e), folded into Q so flash uses raw exp2
    constexpr float QSCALE = 1.5f * 0.08838834764831845f * 1.4426950408889634f;

    (void)hipFuncSetAttribute((const void*)flash_kernel,
                              hipFuncAttributeMaxDynamicSharedMemorySize, 65536);
    (void)hipFuncSetAttribute((const void*)qkv128_kernel,
                              hipFuncAttributeMaxDynamicSharedMemorySize, 65536);

    cast2_bf16_kernel<<<7168, 256, 0, stream>>>(x, x_bf, 1048576, ctx, ctx_bf, 786432);
    transpose4_kernel<<<dim3(32, 32, 4), dim3(32, 8), 0, stream>>>(
        Wq, Wk, Wv, Wout, Wqt, Wkt, Wvt, Woutt);

    // grid: x = head/N-tile (8), y = M-tile (32), z = {Q,K,V}
    qkv128_kernel<<<dim3(8, 32, 3), 256, 65536, stream>>>(
        x_bf, ctx_bf, Wqt, Wkt, Wvt, Qh, Kh, Vt, QSCALE);

    // grid: x = q-block (128 rows), y = head, z = k-split; 512 blocks = 2 per CU
    flash_kernel<<<dim3(32, 8, 2), 256, 65536, stream>>>(Qh, Kh, Vt, Oh, Ohp1, lp);
    combine_kernel<<<2048, 256, 0, stream>>>(Oh, Ohp1, lp, Oh);

    gemm_bf16_kernel<<<dim3(16, 32), 256, 0, stream>>>(Oh, Woutt, 1024, out, bout, 3, 1.0f);
}